// Round 14
// baseline (108.671 us; speedup 1.0000x reference)
//
#include <hip/hip_runtime.h>
#include <hip/hip_bf16.h>

// B=8, N=1024, D=768, H=12, HD=64, SCALE=0.125; M = B*N = 8192
// QKV GEMM: [8192,768]x[768,2304]; proj: [8192,768]x[768,768]
// Q is prescaled by SCALE*log2(e); softmax runs in exp2 domain with NO max
// subtraction (bounded scores), exact after the final divide.
// SYNC RULE (learned R9/R11/R13): raw s_barrier is NOT an LLVM memory fence;
// global_load_lds can be hoisted across it -> races. All LDS double-buffer
// loops here use __syncthreads() (fence + barrier). Counted-vmcnt schedules
// are condemned for this kernel set (3 races, ~1.5us measured upside).
// qkv/proj: 512 threads / 8 waves -> 4 waves/SIMD to hide the barrier drain.

typedef short bf16x8 __attribute__((ext_vector_type(8)));
typedef short bf16x4 __attribute__((ext_vector_type(4)));
typedef float f32x4 __attribute__((ext_vector_type(4)));

#define QSCALE 0.18033688011112042f  // 0.125 * log2(e)

__device__ inline short f2bf(float f) {
    __hip_bfloat16 h = __float2bfloat16(f);
    return __builtin_bit_cast(short, h);
}

// v_cvt_pk_bf16_f32: two f32 -> packed 2x bf16 (RNE). Plain VALU asm, safe.
__device__ inline unsigned cvtpk(float a, float b) {
    unsigned r;
    asm("v_cvt_pk_bf16_f32 %0, %1, %2" : "=v"(r) : "v"(a), "v"(b));
    return r;
}

// K=16 bf16 MFMA via intrinsic (compiler owns regalloc/hazards).
__device__ inline f32x4 mfma16(bf16x4 a, bf16x4 b, f32x4 c) {
    return __builtin_amdgcn_mfma_f32_16x16x16bf16_1k(a, b, c, 0, 0, 0);
}

// LDS rows are 128 B (64 bf16). XOR-swizzle: logical (row, byte) -> physical.
#define BKB 128
__device__ inline int swz(int row, int byte_in_row) {
    return (row * BKB + byte_in_row) ^ ((row & 7) << 4);
}

// global -> LDS direct, 16 B per lane. LDS dest is wave-uniform base + lane*16.
__device__ inline void gload_lds16(const void* g, void* l) {
    __builtin_amdgcn_global_load_lds(
        (const __attribute__((address_space(1))) unsigned int*)g,
        (__attribute__((address_space(3))) unsigned int*)l, 16, 0, 0);
}
// Inverse-swizzle staging: slot-group k (64 slots of 16B), lane L stages
// logical chunk (row = k*8 + (L>>3), c16 = (L&7) ^ ((L>>3)&7)); reading with
// swz() then returns logical data.

// Stage one 128x64 bf16 tile pair (A,B) with 8 waves: 4 loads per wave.
__device__ inline void stage_tile8(const __hip_bfloat16* __restrict__ gA,
                                   const __hip_bfloat16* __restrict__ gB,
                                   char* As, char* Bs, int wid, int sr, int sc16) {
#pragma unroll
    for (int j = 0; j < 2; ++j) {
        int slotbase = (wid * 2 + j) * 64;
        int r = (slotbase >> 3) + sr;
        gload_lds16(gA + (size_t)r * 768 + sc16 * 8, As + slotbase * 16);
        gload_lds16(gB + (size_t)r * 768 + sc16 * 8, Bs + slotbase * 16);
    }
}

// One BK=64 MFMA step, 8-wave version: wave (wr,wc) owns a 64x32 sub-tile.
__device__ inline void gemm_step8(const char* As, const char* Bs, f32x4 acc[4][2],
                                  int wr, int wc, int lh, int lq) {
#pragma unroll
    for (int kki = 0; kki < 2; ++kki) {
        int kk = kki * 32;
        bf16x8 a[4], b[2];
#pragma unroll
        for (int mi = 0; mi < 4; ++mi)
            a[mi] = *(const bf16x8*)(As + swz(wr * 64 + mi * 16 + lh, (kk + lq * 8) * 2));
#pragma unroll
        for (int ni = 0; ni < 2; ++ni)
            b[ni] = *(const bf16x8*)(Bs + swz(wc * 32 + ni * 16 + lh, (kk + lq * 8) * 2));
#pragma unroll
        for (int mi = 0; mi < 4; ++mi)
#pragma unroll
            for (int ni = 0; ni < 2; ++ni)
                acc[mi][ni] = __builtin_amdgcn_mfma_f32_16x16x32_bf16(a[mi], b[ni], acc[mi][ni], 0, 0, 0);
    }
}

// ---------------------------------------------------------------------------
// Fused prep: blocks [0,1728) transpose w_qkv, [1728,2304) transpose w_proj,
// [2304,3072) cast X f32->bf16.
// ---------------------------------------------------------------------------
__device__ inline void transpose_body(const float* __restrict__ src,
                                      __hip_bfloat16* __restrict__ dst,
                                      int R, int C, int bx, int by,
                                      float (*tile)[33]) {
    int c0 = bx * 32, r0 = by * 32;
    int tx = threadIdx.x & 31, ty = threadIdx.x >> 5;
#pragma unroll
    for (int i = 0; i < 32; i += 8)
        tile[ty + i][tx] = src[(size_t)(r0 + ty + i) * C + c0 + tx];
    __syncthreads();
#pragma unroll
    for (int i = 0; i < 32; i += 8)
        dst[(size_t)(c0 + ty + i) * R + r0 + tx] = __float2bfloat16(tile[tx][ty + i]);
}

__global__ __launch_bounds__(256) void prep(const float* __restrict__ x,
                                            const float* __restrict__ w_qkv,
                                            const float* __restrict__ w_proj,
                                            __hip_bfloat16* __restrict__ Xb,
                                            __hip_bfloat16* __restrict__ wqt,
                                            __hip_bfloat16* __restrict__ wpt) {
    __shared__ float tile[32][33];
    const int bid = blockIdx.x;
    if (bid < 1728) {                       // w_qkv: [768][2304] -> [2304][768]
        transpose_body(w_qkv, wqt, 768, 2304, bid % 72, bid / 72, tile);
    } else if (bid < 2304) {                // w_proj: [768][768] -> transposed
        int b2 = bid - 1728;
        transpose_body(w_proj, wpt, 768, 768, b2 % 24, b2 / 24, tile);
    } else {                                // cast X (8 bf16 per thread-iter)
        int b3 = bid - 2304;
        const int n8 = 8192 * 768 / 8;
        for (int i = b3 * 256 + threadIdx.x; i < n8; i += 768 * 256) {
            float4 a = ((const float4*)x)[i * 2];
            float4 b = ((const float4*)x)[i * 2 + 1];
            union { short s[8]; uint4 v; } u;
            u.s[0] = f2bf(a.x); u.s[1] = f2bf(a.y); u.s[2] = f2bf(a.z); u.s[3] = f2bf(a.w);
            u.s[4] = f2bf(b.x); u.s[5] = f2bf(b.y); u.s[6] = f2bf(b.z); u.s[7] = f2bf(b.w);
            ((uint4*)Xb)[i] = u.v;
        }
    }
}

// ---------------------------------------------------------------------------
// QKV GEMM: 512 threads / 8 waves, __syncthreads double-buffer (R8-proven
// schedule): stage(t+1) -> compute(t) -> __syncthreads.
// ---------------------------------------------------------------------------
__global__ __launch_bounds__(512) void qkv_gemm(const __hip_bfloat16* __restrict__ Xb,
                                                const __hip_bfloat16* __restrict__ Wt,
                                                const float* __restrict__ bias,
                                                __hip_bfloat16* __restrict__ Qo,
                                                __hip_bfloat16* __restrict__ Ko,
                                                __hip_bfloat16* __restrict__ Vto) {
    __shared__ __align__(16) char As0[16384], Bs0[16384], As1[16384], Bs1[16384];
    const int orig = blockIdx.y * 18 + blockIdx.x;       // nwg = 1152, %8 == 0
    const int swzid = (orig & 7) * 144 + (orig >> 3);    // XCD-contiguous chunks
    const int m0 = (swzid / 18) * 128;
    const int n0 = (swzid % 18) * 128;
    const int tid = threadIdx.x;
    const int lane = tid & 63, wid = tid >> 6;           // 8 waves
    const int wr = wid >> 2, wc = wid & 3;               // 2 x 4 wave grid
    const int lh = lane & 15, lq = lane >> 4;
    const int sr = lane >> 3;
    const int sc16 = (lane & 7) ^ (sr & 7);

    const __hip_bfloat16* gA = Xb + (size_t)m0 * 768;
    const __hip_bfloat16* gB = Wt + (size_t)n0 * 768;

    f32x4 acc[4][2] = {};

    stage_tile8(gA, gB, As0, Bs0, wid, sr, sc16);
    __syncthreads();
#pragma unroll
    for (int t = 0; t < 12; t += 2) {
        stage_tile8(gA + (t + 1) * 64, gB + (t + 1) * 64, As1, Bs1, wid, sr, sc16);
        gemm_step8(As0, Bs0, acc, wr, wc, lh, lq);
        __syncthreads();
        if (t + 2 < 12)
            stage_tile8(gA + (t + 2) * 64, gB + (t + 2) * 64, As0, Bs0, wid, sr, sc16);
        gemm_step8(As1, Bs1, acc, wr, wc, lh, lq);
        __syncthreads();
    }

#pragma unroll
    for (int ni = 0; ni < 2; ++ni) {
        int col = n0 + wc * 32 + ni * 16 + lh;
        float bv = bias[col];
        int which = col / 768;
        int rem = col - which * 768;
        int h = rem >> 6, hd = rem & 63;
        if (which == 2) {
#pragma unroll
            for (int mi = 0; mi < 4; ++mi) {
                int row0 = m0 + wr * 64 + mi * 16 + lq * 4;
                int bb = row0 >> 10, rr0 = row0 & 1023;
                int head = bb * 12 + h;
                bf16x4 pk;
#pragma unroll
                for (int j = 0; j < 4; ++j) pk[j] = f2bf(acc[mi][ni][j] + bv);
                *(bf16x4*)(Vto + ((size_t)head * 64 + hd) * 1024 + rr0) = pk;
            }
        } else {
            const float sc = (which == 0) ? QSCALE : 1.f;
            __hip_bfloat16* dst = (which == 0) ? Qo : Ko;
#pragma unroll
            for (int mi = 0; mi < 4; ++mi) {
#pragma unroll
                for (int j = 0; j < 4; ++j) {
                    int row = m0 + wr * 64 + mi * 16 + lq * 4 + j;
                    int bb = row >> 10, rr = row & 1023;
                    int head = bb * 12 + h;
                    dst[((size_t)head * 1024 + rr) * 64 + hd] =
                        __float2bfloat16((acc[mi][ni][j] + bv) * sc);
                }
            }
        }
    }
}

// ---------------------------------------------------------------------------
// Flash attention (R8/R10/R12-proven): swapped-QK^T, exp2, no-max softmax,
// register-PV, MFMA row sums. 2-buffer LDS, __syncthreads per step.
// ---------------------------------------------------------------------------
__global__ __launch_bounds__(256, 3) void attn_kernel(const __hip_bfloat16* __restrict__ Q,
                                                      const __hip_bfloat16* __restrict__ K,
                                                      const __hip_bfloat16* __restrict__ Vt,
                                                      __hip_bfloat16* __restrict__ Ao) {
    __shared__ __align__(16) char kvlds[2 * 16384];  // [buf][K 8K | V 8K]
    const int head = blockIdx.x;   // grid.x = 96 -> head%8 = XCD (L2 locality)
    const int qt = blockIdx.y;
    const int tid = threadIdx.x;
    const int lane = tid & 63, w = tid >> 6;
    const int lh = lane & 15, lq = lane >> 4;
    const int q0 = qt * 128 + w * 32;
    const size_t hoff = (size_t)head * 65536;
    const __hip_bfloat16* Kg = K + hoff;
    const __hip_bfloat16* Vg = Vt + hoff;
    const int sr = lane >> 3;
    const int sc16 = (lane & 7) ^ (sr & 7);

    // Hoisted swizzled LDS-read address parts.
    const int mfield = (lh & 7) << 4;
    const int rowb = lh * 128;
    const int kb0 = (lq * 16) ^ mfield;           // QK, kki=0
    const int kb1 = (64 | (lq * 16)) ^ mfield;    // QK, kki=1
    int vb[4];
#pragma unroll
    for (int kf = 0; kf < 4; ++kf) vb[kf] = ((kf * 32) | (lq * 8)) ^ mfield;

    const bf16x4 ONES = {0x3F80, 0x3F80, 0x3F80, 0x3F80};  // 1.0 bf16 x4

    bf16x8 qf[2][2];
#pragma unroll
    for (int qi = 0; qi < 2; ++qi)
#pragma unroll
        for (int kki = 0; kki < 2; ++kki)
            qf[qi][kki] = *(const bf16x8*)(Q + hoff + (size_t)(q0 + qi * 16 + lh) * 64 + kki * 32 + lq * 8);

    f32x4 accT[2][4] = {};
    f32x4 accL[2] = {};   // ones-MFMA row-sum: every lane gets l for q=lh

    // Staging pointers (advance per tile: K +64 rows, Vt +64 cols).
    const __hip_bfloat16* kg0 = Kg + (size_t)((w * 2) * 8 + sr) * 64 + sc16 * 8;
    const __hip_bfloat16* kg1 = kg0 + 8 * 64;
    const __hip_bfloat16* vg0 = Vg + (size_t)((w * 2) * 8 + sr) * 1024 + sc16 * 8;
    const __hip_bfloat16* vg1 = vg0 + 8 * 1024;
    const int kd = (w * 2) * 1024;  // this wave's K slot pair offset

    gload_lds16(kg0, kvlds + kd);
    gload_lds16(kg1, kvlds + kd + 1024);
    gload_lds16(vg0, kvlds + 8192 + kd);
    gload_lds16(vg1, kvlds + 8192 + kd + 1024);
    kg0 += 4096; kg1 += 4096; vg0 += 64; vg1 += 64;
    __syncthreads();

    auto step = [&](int kt, char* Ks, char* Vs, char* Kn) {
        if (kt < 15) {  // prefetch tile kt+1 into other buffer
            gload_lds16(kg0, Kn + kd);
            gload_lds16(kg1, Kn + kd + 1024);
            gload_lds16(vg0, Kn + 8192 + kd);
            gload_lds16(vg1, Kn + 8192 + kd + 1024);
            kg0 += 4096; kg1 += 4096; vg0 += 64; vg1 += 64;
        }
        // S^T = mfma(K, Q): lane holds q = q0+qi*16+lh, k = kf*16+lq*4+j
        f32x4 sT[2][4] = {};
        __builtin_amdgcn_s_setprio(1);
#pragma unroll
        for (int kf = 0; kf < 4; ++kf) {
            bf16x8 k0v = *(const bf16x8*)(Ks + rowb + kf * 2048 + kb0);
            sT[0][kf] = __builtin_amdgcn_mfma_f32_16x16x32_bf16(k0v, qf[0][0], sT[0][kf], 0, 0, 0);
            sT[1][kf] = __builtin_amdgcn_mfma_f32_16x16x32_bf16(k0v, qf[1][0], sT[1][kf], 0, 0, 0);
            bf16x8 k1v = *(const bf16x8*)(Ks + rowb + kf * 2048 + kb1);
            sT[0][kf] = __builtin_amdgcn_mfma_f32_16x16x32_bf16(k1v, qf[0][1], sT[0][kf], 0, 0, 0);
            sT[1][kf] = __builtin_amdgcn_mfma_f32_16x16x32_bf16(k1v, qf[1][1], sT[1][kf], 0, 0, 0);
        }
        __builtin_amdgcn_s_setprio(0);
        // P = exp2(S), pack to bf16 (stays in registers)
        bf16x4 pb[2][4];
#pragma unroll
        for (int qi = 0; qi < 2; ++qi) {
#pragma unroll
            for (int kf = 0; kf < 4; ++kf) {
                float p0 = __builtin_amdgcn_exp2f(sT[qi][kf][0]);
                float p1 = __builtin_amdgcn_exp2f(sT[qi][kf][1]);
                float p2 = __builtin_amdgcn_exp2f(sT[qi][kf][2]);
                float p3 = __builtin_amdgcn_exp2f(sT[qi][kf][3]);
                union { unsigned u[2]; bf16x4 v; } uu;
                uu.u[0] = cvtpk(p0, p1);
                uu.u[1] = cvtpk(p2, p3);
                pb[qi][kf] = uu.v;
            }
        }
        // O^T += Vt x P; l += 1s x P  (all on the MFMA pipe)
        __builtin_amdgcn_s_setprio(1);
#pragma unroll
        for (int kf = 0; kf < 4; ++kf) {
            accL[0] = mfma16(ONES, pb[0][kf], accL[0]);
            accL[1] = mfma16(ONES, pb[1][kf], accL[1]);
#pragma unroll
            for (int hf = 0; hf < 4; ++hf) {
                bf16x4 vfr = *(const bf16x4*)(Vs + rowb + hf * 2048 + vb[kf]);
                accT[0][hf] = mfma16(vfr, pb[0][kf], accT[0][hf]);
                accT[1][hf] = mfma16(vfr, pb[1][kf], accT[1][hf]);
            }
        }
        __builtin_amdgcn_s_setprio(0);
        __syncthreads();  // drains gload_lds (vmcnt) + guards buffer reuse
    };

#pragma unroll 1
    for (int kt2 = 0; kt2 < 16; kt2 += 2) {
        step(kt2, kvlds, kvlds + 8192, kvlds + 16384);
        step(kt2 + 1, kvlds + 16384, kvlds + 16384 + 8192, kvlds);
    }

    const int b = head / 12, h = head - (head / 12) * 12;
#pragma unroll
    for (int qi = 0; qi < 2; ++qi) {
        float inv = 1.f / accL[qi][0];
        int q = q0 + qi * 16 + lh;
#pragma unroll
        for (int hf = 0; hf < 4; ++hf) {
            bf16x4 pk;
#pragma unroll
            for (int j = 0; j < 4; ++j) pk[j] = f2bf(accT[qi][hf][j] * inv);
            *(bf16x4*)(Ao + ((size_t)(b * 1024 + q)) * 768 + h * 64 + hf * 16 + lq * 4) = pk;
        }
    }
}

// ---------------------------------------------------------------------------
// Proj GEMM: 512 threads / 8 waves, __syncthreads double-buffer.
// ---------------------------------------------------------------------------
__global__ __launch_bounds__(512) void proj_gemm(const __hip_bfloat16* __restrict__ A,
                                                 const __hip_bfloat16* __restrict__ Wt,
                                                 const float* __restrict__ bias,
                                                 float* __restrict__ Out) {
    __shared__ __align__(16) char As0[16384], Bs0[16384], As1[16384], Bs1[16384];
    const int orig = blockIdx.y * 6 + blockIdx.x;        // nwg = 384, %8 == 0
    const int swzid = (orig & 7) * 48 + (orig >> 3);
    const int m0 = (swzid / 6) * 128;
    const int n0 = (swzid % 6) * 128;
    const int tid = threadIdx.x;
    const int lane = tid & 63, wid = tid >> 6;
    const int wr = wid >> 2, wc = wid & 3;
    const int lh = lane & 15, lq = lane >> 4;
    const int sr = lane >> 3;
    const int sc16 = (lane & 7) ^ (sr & 7);

    const __hip_bfloat16* gA = A + (size_t)m0 * 768;
    const __hip_bfloat16* gB = Wt + (size_t)n0 * 768;

    f32x4 acc[4][2] = {};

    stage_tile8(gA, gB, As0, Bs0, wid, sr, sc16);
    __syncthreads();
#pragma unroll
    for (int t = 0; t < 12; t += 2) {
        stage_tile8(gA + (t + 1) * 64, gB + (t + 1) * 64, As1, Bs1, wid, sr, sc16);
        gemm_step8(As0, Bs0, acc, wr, wc, lh, lq);
        __syncthreads();
        if (t + 2 < 12)
            stage_tile8(gA + (t + 2) * 64, gB + (t + 2) * 64, As0, Bs0, wid, sr, sc16);
        gemm_step8(As1, Bs1, acc, wr, wc, lh, lq);
        __syncthreads();
    }

#pragma unroll
    for (int ni = 0; ni < 2; ++ni) {
        int col = n0 + wc * 32 + ni * 16 + lh;
        float bv = bias[col];
#pragma unroll
        for (int mi = 0; mi < 4; ++mi) {
#pragma unroll
            for (int j = 0; j < 4; ++j) {
                int row = m0 + wr * 64 + mi * 16 + lq * 4 + j;
                Out[(size_t)row * 768 + col] = acc[mi][ni][j] + bv;
            }
        }
    }
}

// ---------------------------------------------------------------------------
extern "C" void kernel_launch(void* const* d_in, const int* in_sizes, int n_in,
                              void* d_out, int out_size, void* d_ws, size_t ws_size,
                              hipStream_t stream) {
    const float* x      = (const float*)d_in[0];
    const float* w_qkv  = (const float*)d_in[1];
    const float* b_qkv  = (const float*)d_in[2];
    const float* w_proj = (const float*)d_in[3];
    const float* b_proj = (const float*)d_in[4];
    float* out = (float*)d_out;

    __hip_bfloat16* ws = (__hip_bfloat16*)d_ws;
    __hip_bfloat16* wqt = ws;                       // [2304][768]
    __hip_bfloat16* wpt = wqt + 2304 * 768;         // [768][768]
    __hip_bfloat16* Qb  = wpt + 768 * 768;          // [96][1024][64]
    __hip_bfloat16* Kb  = Qb + 96 * 1024 * 64;      // [96][1024][64]
    __hip_bfloat16* Vt  = Kb + 96 * 1024 * 64;      // [96][64][1024]
    __hip_bfloat16* Ao  = Vt + 96 * 1024 * 64;      // [8192][768]
    __hip_bfloat16* Xb  = Ao + 8192 * 768;          // [8192][768]

    prep<<<3072, 256, 0, stream>>>(x, w_qkv, w_proj, Xb, wqt, wpt);
    qkv_gemm<<<dim3(18, 64), 512, 0, stream>>>(Xb, wqt, b_qkv, Qb, Kb, Vt);
    attn_kernel<<<dim3(96, 8), 256, 0, stream>>>(Qb, Kb, Vt, Ao);
    proj_gemm<<<dim3(6, 64), 512, 0, stream>>>(Ao, wpt, b_proj, out);
}

// Round 15
// 100.719 us; speedup vs baseline: 1.0789x; 1.0789x over previous
//
#include <hip/hip_runtime.h>
#include <hip/hip_bf16.h>

// B=8, N=1024, D=768, H=12, HD=64, SCALE=0.125; M = B*N = 8192
// QKV GEMM: [8192,768]x[768,2304]; proj: [8192,768]x[768,768]
// Q is prescaled by SCALE*log2(e) so attention softmax runs in exp2 domain.
// Softmax uses NO max subtraction (scores bounded), exact after final divide.
// qkv/proj: counted s_waitcnt vmcnt(N) + builtin s_barrier (R10/R12-validated
// at 256 threads). attn: R8/R10/R12-proven __syncthreads 2-buffer pipeline.
// R14's 512-thread variants refuted (qkv unchanged, proj +8us) -> reverted.

typedef short bf16x8 __attribute__((ext_vector_type(8)));
typedef short bf16x4 __attribute__((ext_vector_type(4)));
typedef float f32x4 __attribute__((ext_vector_type(4)));

#define QSCALE 0.18033688011112042f  // 0.125 * log2(e)

#define WAIT_VM(N) asm volatile("s_waitcnt vmcnt(" #N ")" ::: "memory")

__device__ inline short f2bf(float f) {
    __hip_bfloat16 h = __float2bfloat16(f);
    return __builtin_bit_cast(short, h);
}

// v_cvt_pk_bf16_f32: two f32 -> packed 2x bf16 (RNE). Plain VALU asm, safe.
__device__ inline unsigned cvtpk(float a, float b) {
    unsigned r;
    asm("v_cvt_pk_bf16_f32 %0, %1, %2" : "=v"(r) : "v"(a), "v"(b));
    return r;
}

// K=16 bf16 MFMA via intrinsic (compiler owns regalloc/hazards; inline-asm
// MFMA was silently corrupt in R5-R7). B-frag layout == QK^T C-layout.
__device__ inline f32x4 mfma16(bf16x4 a, bf16x4 b, f32x4 c) {
    return __builtin_amdgcn_mfma_f32_16x16x16bf16_1k(a, b, c, 0, 0, 0);
}

// LDS rows are 128 B (64 bf16). XOR-swizzle: logical (row, byte) -> physical.
#define BKB 128
__device__ inline int swz(int row, int byte_in_row) {
    return (row * BKB + byte_in_row) ^ ((row & 7) << 4);
}

// global -> LDS direct, 16 B per lane. LDS dest is wave-uniform base + lane*16.
__device__ inline void gload_lds16(const void* g, void* l) {
    __builtin_amdgcn_global_load_lds(
        (const __attribute__((address_space(1))) unsigned int*)g,
        (__attribute__((address_space(3))) unsigned int*)l, 16, 0, 0);
}
// Inverse-swizzle staging: slot-group k (64 slots of 16B), lane L stages
// logical chunk (row = k*8 + (L>>3), c16 = (L&7) ^ ((L>>3)&7)); reading with
// swz() then returns logical data.

// Stage one 128x64 bf16 tile pair (A,B): 8 loads per wave (4 waves).
__device__ inline void stage_tile(const __hip_bfloat16* __restrict__ gA,
                                  const __hip_bfloat16* __restrict__ gB,
                                  char* As, char* Bs, int wid, int sr, int sc16) {
#pragma unroll
    for (int j = 0; j < 4; ++j) {
        int slotbase = (wid * 4 + j) * 64;
        int r = (slotbase >> 3) + sr;
        gload_lds16(gA + (size_t)r * 768 + sc16 * 8, As + slotbase * 16);
        gload_lds16(gB + (size_t)r * 768 + sc16 * 8, Bs + slotbase * 16);
    }
}

// One BK=64 MFMA step from staged tiles (4 waves, 64x64 per wave).
__device__ inline void gemm_step(const char* As, const char* Bs, f32x4 acc[4][4],
                                 int wr, int wc, int lh, int lq) {
#pragma unroll
    for (int kki = 0; kki < 2; ++kki) {
        int kk = kki * 32;
        bf16x8 a[4], b[4];
#pragma unroll
        for (int mi = 0; mi < 4; ++mi)
            a[mi] = *(const bf16x8*)(As + swz(wr * 64 + mi * 16 + lh, (kk + lq * 8) * 2));
#pragma unroll
        for (int ni = 0; ni < 4; ++ni)
            b[ni] = *(const bf16x8*)(Bs + swz(wc * 64 + ni * 16 + lh, (kk + lq * 8) * 2));
#pragma unroll
        for (int mi = 0; mi < 4; ++mi)
#pragma unroll
            for (int ni = 0; ni < 4; ++ni)
                acc[mi][ni] = __builtin_amdgcn_mfma_f32_16x16x32_bf16(a[mi], b[ni], acc[mi][ni], 0, 0, 0);
    }
}

// ---------------------------------------------------------------------------
// Fused prep: blocks [0,1728) transpose w_qkv, [1728,2304) transpose w_proj,
// [2304,3072) cast X f32->bf16.
// ---------------------------------------------------------------------------
__device__ inline void transpose_body(const float* __restrict__ src,
                                      __hip_bfloat16* __restrict__ dst,
                                      int R, int C, int bx, int by,
                                      float (*tile)[33]) {
    int c0 = bx * 32, r0 = by * 32;
    int tx = threadIdx.x & 31, ty = threadIdx.x >> 5;
#pragma unroll
    for (int i = 0; i < 32; i += 8)
        tile[ty + i][tx] = src[(size_t)(r0 + ty + i) * C + c0 + tx];
    __syncthreads();
#pragma unroll
    for (int i = 0; i < 32; i += 8)
        dst[(size_t)(c0 + ty + i) * R + r0 + tx] = __float2bfloat16(tile[tx][ty + i]);
}

__global__ __launch_bounds__(256) void prep(const float* __restrict__ x,
                                            const float* __restrict__ w_qkv,
                                            const float* __restrict__ w_proj,
                                            __hip_bfloat16* __restrict__ Xb,
                                            __hip_bfloat16* __restrict__ wqt,
                                            __hip_bfloat16* __restrict__ wpt) {
    __shared__ float tile[32][33];
    const int bid = blockIdx.x;
    if (bid < 1728) {                       // w_qkv: [768][2304] -> [2304][768]
        transpose_body(w_qkv, wqt, 768, 2304, bid % 72, bid / 72, tile);
    } else if (bid < 2304) {                // w_proj: [768][768] -> transposed
        int b2 = bid - 1728;
        transpose_body(w_proj, wpt, 768, 768, b2 % 24, b2 / 24, tile);
    } else {                                // cast X (8 bf16 per thread-iter)
        int b3 = bid - 2304;
        const int n8 = 8192 * 768 / 8;
        for (int i = b3 * 256 + threadIdx.x; i < n8; i += 768 * 256) {
            float4 a = ((const float4*)x)[i * 2];
            float4 b = ((const float4*)x)[i * 2 + 1];
            union { short s[8]; uint4 v; } u;
            u.s[0] = f2bf(a.x); u.s[1] = f2bf(a.y); u.s[2] = f2bf(a.z); u.s[3] = f2bf(a.w);
            u.s[4] = f2bf(b.x); u.s[5] = f2bf(b.y); u.s[6] = f2bf(b.z); u.s[7] = f2bf(b.w);
            ((uint4*)Xb)[i] = u.v;
        }
    }
}

// ---------------------------------------------------------------------------
// QKV GEMM, counted-vmcnt double-buffered (R10/R12-validated). Per K-step:
// stage(t+1) -> vmcnt(8) -> barrier -> MFMA -> barrier.
// ---------------------------------------------------------------------------
__global__ __launch_bounds__(256) void qkv_gemm(const __hip_bfloat16* __restrict__ Xb,
                                                const __hip_bfloat16* __restrict__ Wt,
                                                const float* __restrict__ bias,
                                                __hip_bfloat16* __restrict__ Qo,
                                                __hip_bfloat16* __restrict__ Ko,
                                                __hip_bfloat16* __restrict__ Vto) {
    __shared__ __align__(16) char As0[16384], Bs0[16384], As1[16384], Bs1[16384];
    char* Asb[2] = {As0, As1};
    char* Bsb[2] = {Bs0, Bs1};
    const int orig = blockIdx.y * 18 + blockIdx.x;       // nwg = 1152, %8 == 0
    const int swzid = (orig & 7) * 144 + (orig >> 3);    // XCD-contiguous chunks
    const int m0 = (swzid / 18) * 128;
    const int n0 = (swzid % 18) * 128;
    const int tid = threadIdx.x;
    const int lane = tid & 63, wid = tid >> 6;
    const int wr = wid >> 1, wc = wid & 1;
    const int lh = lane & 15, lq = lane >> 4;
    const int sr = lane >> 3;
    const int sc16 = (lane & 7) ^ (sr & 7);

    const __hip_bfloat16* gA = Xb + (size_t)m0 * 768;
    const __hip_bfloat16* gB = Wt + (size_t)n0 * 768;

    f32x4 acc[4][4] = {};

    stage_tile(gA, gB, As0, Bs0, wid, sr, sc16);
#pragma unroll
    for (int t = 0; t < 12; ++t) {
        if (t < 11) {
            stage_tile(gA + (t + 1) * 64, gB + (t + 1) * 64,
                       Asb[(t + 1) & 1], Bsb[(t + 1) & 1], wid, sr, sc16);
            WAIT_VM(8);
        } else {
            WAIT_VM(0);
        }
        __builtin_amdgcn_sched_barrier(0);
        __builtin_amdgcn_s_barrier();   // tile t staged everywhere
        gemm_step(Asb[t & 1], Bsb[t & 1], acc, wr, wc, lh, lq);
        __builtin_amdgcn_s_barrier();   // reads done before buffer reuse
    }

#pragma unroll
    for (int ni = 0; ni < 4; ++ni) {
        int col = n0 + wc * 64 + ni * 16 + lh;
        float bv = bias[col];
        int which = col / 768;
        int rem = col - which * 768;
        int h = rem >> 6, hd = rem & 63;
        if (which == 2) {
#pragma unroll
            for (int mi = 0; mi < 4; ++mi) {
                int row0 = m0 + wr * 64 + mi * 16 + lq * 4;
                int bb = row0 >> 10, rr0 = row0 & 1023;
                int head = bb * 12 + h;
                bf16x4 pk;
#pragma unroll
                for (int j = 0; j < 4; ++j) pk[j] = f2bf(acc[mi][ni][j] + bv);
                *(bf16x4*)(Vto + ((size_t)head * 64 + hd) * 1024 + rr0) = pk;
            }
        } else {
            const float sc = (which == 0) ? QSCALE : 1.f;
            __hip_bfloat16* dst = (which == 0) ? Qo : Ko;
#pragma unroll
            for (int mi = 0; mi < 4; ++mi) {
#pragma unroll
                for (int j = 0; j < 4; ++j) {
                    int row = m0 + wr * 64 + mi * 16 + lq * 4 + j;
                    int bb = row >> 10, rr = row & 1023;
                    int head = bb * 12 + h;
                    dst[((size_t)head * 1024 + rr) * 64 + hd] =
                        __float2bfloat16((acc[mi][ni][j] + bv) * sc);
                }
            }
        }
    }
}

// ---------------------------------------------------------------------------
// Flash attention (R8/R10/R12-proven): swapped-QK^T, exp2, no-max softmax,
// register-PV, MFMA row sums. 2-buffer LDS, __syncthreads per step.
// ---------------------------------------------------------------------------
__global__ __launch_bounds__(256, 3) void attn_kernel(const __hip_bfloat16* __restrict__ Q,
                                                      const __hip_bfloat16* __restrict__ K,
                                                      const __hip_bfloat16* __restrict__ Vt,
                                                      __hip_bfloat16* __restrict__ Ao) {
    __shared__ __align__(16) char kvlds[2 * 16384];  // [buf][K 8K | V 8K]
    const int head = blockIdx.x;   // grid.x = 96 -> head%8 = XCD (L2 locality)
    const int qt = blockIdx.y;
    const int tid = threadIdx.x;
    const int lane = tid & 63, w = tid >> 6;
    const int lh = lane & 15, lq = lane >> 4;
    const int q0 = qt * 128 + w * 32;
    const size_t hoff = (size_t)head * 65536;
    const __hip_bfloat16* Kg = K + hoff;
    const __hip_bfloat16* Vg = Vt + hoff;
    const int sr = lane >> 3;
    const int sc16 = (lane & 7) ^ (sr & 7);

    // Hoisted swizzled LDS-read address parts.
    const int mfield = (lh & 7) << 4;
    const int rowb = lh * 128;
    const int kb0 = (lq * 16) ^ mfield;           // QK, kki=0
    const int kb1 = (64 | (lq * 16)) ^ mfield;    // QK, kki=1
    int vb[4];
#pragma unroll
    for (int kf = 0; kf < 4; ++kf) vb[kf] = ((kf * 32) | (lq * 8)) ^ mfield;

    const bf16x4 ONES = {0x3F80, 0x3F80, 0x3F80, 0x3F80};  // 1.0 bf16 x4

    bf16x8 qf[2][2];
#pragma unroll
    for (int qi = 0; qi < 2; ++qi)
#pragma unroll
        for (int kki = 0; kki < 2; ++kki)
            qf[qi][kki] = *(const bf16x8*)(Q + hoff + (size_t)(q0 + qi * 16 + lh) * 64 + kki * 32 + lq * 8);

    f32x4 accT[2][4] = {};
    f32x4 accL[2] = {};   // ones-MFMA row-sum: every lane gets l for q=lh

    // Staging pointers (advance per tile: K +64 rows, Vt +64 cols).
    const __hip_bfloat16* kg0 = Kg + (size_t)((w * 2) * 8 + sr) * 64 + sc16 * 8;
    const __hip_bfloat16* kg1 = kg0 + 8 * 64;
    const __hip_bfloat16* vg0 = Vg + (size_t)((w * 2) * 8 + sr) * 1024 + sc16 * 8;
    const __hip_bfloat16* vg1 = vg0 + 8 * 1024;
    const int kd = (w * 2) * 1024;  // this wave's K slot pair offset

    gload_lds16(kg0, kvlds + kd);
    gload_lds16(kg1, kvlds + kd + 1024);
    gload_lds16(vg0, kvlds + 8192 + kd);
    gload_lds16(vg1, kvlds + 8192 + kd + 1024);
    kg0 += 4096; kg1 += 4096; vg0 += 64; vg1 += 64;
    __syncthreads();

    auto step = [&](int kt, char* Ks, char* Vs, char* Kn) {
        if (kt < 15) {  // prefetch tile kt+1 into other buffer
            gload_lds16(kg0, Kn + kd);
            gload_lds16(kg1, Kn + kd + 1024);
            gload_lds16(vg0, Kn + 8192 + kd);
            gload_lds16(vg1, Kn + 8192 + kd + 1024);
            kg0 += 4096; kg1 += 4096; vg0 += 64; vg1 += 64;
        }
        // S^T = mfma(K, Q): lane holds q = q0+qi*16+lh, k = kf*16+lq*4+j
        f32x4 sT[2][4] = {};
        __builtin_amdgcn_s_setprio(1);
#pragma unroll
        for (int kf = 0; kf < 4; ++kf) {
            bf16x8 k0v = *(const bf16x8*)(Ks + rowb + kf * 2048 + kb0);
            sT[0][kf] = __builtin_amdgcn_mfma_f32_16x16x32_bf16(k0v, qf[0][0], sT[0][kf], 0, 0, 0);
            sT[1][kf] = __builtin_amdgcn_mfma_f32_16x16x32_bf16(k0v, qf[1][0], sT[1][kf], 0, 0, 0);
            bf16x8 k1v = *(const bf16x8*)(Ks + rowb + kf * 2048 + kb1);
            sT[0][kf] = __builtin_amdgcn_mfma_f32_16x16x32_bf16(k1v, qf[0][1], sT[0][kf], 0, 0, 0);
            sT[1][kf] = __builtin_amdgcn_mfma_f32_16x16x32_bf16(k1v, qf[1][1], sT[1][kf], 0, 0, 0);
        }
        __builtin_amdgcn_s_setprio(0);
        // P = exp2(S), pack to bf16 (stays in registers)
        bf16x4 pb[2][4];
#pragma unroll
        for (int qi = 0; qi < 2; ++qi) {
#pragma unroll
            for (int kf = 0; kf < 4; ++kf) {
                float p0 = __builtin_amdgcn_exp2f(sT[qi][kf][0]);
                float p1 = __builtin_amdgcn_exp2f(sT[qi][kf][1]);
                float p2 = __builtin_amdgcn_exp2f(sT[qi][kf][2]);
                float p3 = __builtin_amdgcn_exp2f(sT[qi][kf][3]);
                union { unsigned u[2]; bf16x4 v; } uu;
                uu.u[0] = cvtpk(p0, p1);
                uu.u[1] = cvtpk(p2, p3);
                pb[qi][kf] = uu.v;
            }
        }
        // O^T += Vt x P; l += 1s x P  (all on the MFMA pipe)
        __builtin_amdgcn_s_setprio(1);
#pragma unroll
        for (int kf = 0; kf < 4; ++kf) {
            accL[0] = mfma16(ONES, pb[0][kf], accL[0]);
            accL[1] = mfma16(ONES, pb[1][kf], accL[1]);
#pragma unroll
            for (int hf = 0; hf < 4; ++hf) {
                bf16x4 vfr = *(const bf16x4*)(Vs + rowb + hf * 2048 + vb[kf]);
                accT[0][hf] = mfma16(vfr, pb[0][kf], accT[0][hf]);
                accT[1][hf] = mfma16(vfr, pb[1][kf], accT[1][hf]);
            }
        }
        __builtin_amdgcn_s_setprio(0);
        __syncthreads();  // drains gload_lds (vmcnt) + guards buffer reuse
    };

#pragma unroll 1
    for (int kt2 = 0; kt2 < 16; kt2 += 2) {
        step(kt2, kvlds, kvlds + 8192, kvlds + 16384);
        step(kt2 + 1, kvlds + 16384, kvlds + 16384 + 8192, kvlds);
    }

    const int b = head / 12, h = head - (head / 12) * 12;
#pragma unroll
    for (int qi = 0; qi < 2; ++qi) {
        float inv = 1.f / accL[qi][0];
        int q = q0 + qi * 16 + lh;
#pragma unroll
        for (int hf = 0; hf < 4; ++hf) {
            bf16x4 pk;
#pragma unroll
            for (int j = 0; j < 4; ++j) pk[j] = f2bf(accT[qi][hf][j] * inv);
            *(bf16x4*)(Ao + ((size_t)(b * 1024 + q)) * 768 + h * 64 + hf * 16 + lq * 4) = pk;
        }
    }
}

// ---------------------------------------------------------------------------
// Proj GEMM, counted-vmcnt double-buffered (R10/R12-validated schedule).
// ---------------------------------------------------------------------------
__global__ __launch_bounds__(256) void proj_gemm(const __hip_bfloat16* __restrict__ A,
                                                 const __hip_bfloat16* __restrict__ Wt,
                                                 const float* __restrict__ bias,
                                                 float* __restrict__ Out) {
    __shared__ __align__(16) char As0[16384], Bs0[16384], As1[16384], Bs1[16384];
    char* Asb[2] = {As0, As1};
    char* Bsb[2] = {Bs0, Bs1};
    const int orig = blockIdx.y * 6 + blockIdx.x;        // nwg = 384, %8 == 0
    const int swzid = (orig & 7) * 48 + (orig >> 3);
    const int m0 = (swzid / 6) * 128;
    const int n0 = (swzid % 6) * 128;
    const int tid = threadIdx.x;
    const int lane = tid & 63, wid = tid >> 6;
    const int wr = wid >> 1, wc = wid & 1;
    const int lh = lane & 15, lq = lane >> 4;
    const int sr = lane >> 3;
    const int sc16 = (lane & 7) ^ (sr & 7);

    const __hip_bfloat16* gA = A + (size_t)m0 * 768;
    const __hip_bfloat16* gB = Wt + (size_t)n0 * 768;

    f32x4 acc[4][4] = {};

    stage_tile(gA, gB, As0, Bs0, wid, sr, sc16);
#pragma unroll
    for (int t = 0; t < 12; ++t) {
        if (t < 11) {
            stage_tile(gA + (t + 1) * 64, gB + (t + 1) * 64,
                       Asb[(t + 1) & 1], Bsb[(t + 1) & 1], wid, sr, sc16);
            WAIT_VM(8);
        } else {
            WAIT_VM(0);
        }
        __builtin_amdgcn_sched_barrier(0);
        __builtin_amdgcn_s_barrier();
        gemm_step(Asb[t & 1], Bsb[t & 1], acc, wr, wc, lh, lq);
        __builtin_amdgcn_s_barrier();
    }

#pragma unroll
    for (int ni = 0; ni < 4; ++ni) {
        int col = n0 + wc * 64 + ni * 16 + lh;
        float bv = bias[col];
#pragma unroll
        for (int mi = 0; mi < 4; ++mi) {
#pragma unroll
            for (int j = 0; j < 4; ++j) {
                int row = m0 + wr * 64 + mi * 16 + lq * 4 + j;
                Out[(size_t)row * 768 + col] = acc[mi][ni][j] + bv;
            }
        }
    }
}

// ---------------------------------------------------------------------------
extern "C" void kernel_launch(void* const* d_in, const int* in_sizes, int n_in,
                              void* d_out, int out_size, void* d_ws, size_t ws_size,
                              hipStream_t stream) {
    const float* x      = (const float*)d_in[0];
    const float* w_qkv  = (const float*)d_in[1];
    const float* b_qkv  = (const float*)d_in[2];
    const float* w_proj = (const float*)d_in[3];
    const float* b_proj = (const float*)d_in[4];
    float* out = (float*)d_out;

    __hip_bfloat16* ws = (__hip_bfloat16*)d_ws;
    __hip_bfloat16* wqt = ws;                       // [2304][768]
    __hip_bfloat16* wpt = wqt + 2304 * 768;         // [768][768]
    __hip_bfloat16* Qb  = wpt + 768 * 768;          // [96][1024][64]
    __hip_bfloat16* Kb  = Qb + 96 * 1024 * 64;      // [96][1024][64]
    __hip_bfloat16* Vt  = Kb + 96 * 1024 * 64;      // [96][64][1024]
    __hip_bfloat16* Ao  = Vt + 96 * 1024 * 64;      // [8192][768]
    __hip_bfloat16* Xb  = Ao + 8192 * 768;          // [8192][768]

    prep<<<3072, 256, 0, stream>>>(x, w_qkv, w_proj, Xb, wqt, wpt);
    qkv_gemm<<<dim3(18, 64), 256, 0, stream>>>(Xb, wqt, b_qkv, Qb, Kb, Vt);
    attn_kernel<<<dim3(96, 8), 256, 0, stream>>>(Qb, Kb, Vt, Ao);
    proj_gemm<<<dim3(6, 64), 256, 0, stream>>>(Ao, wpt, b_proj, out);
}